// Round 8
// baseline (658.362 us; speedup 1.0000x reference)
//
#include <hip/hip_runtime.h>
#include <hip/hip_bf16.h>
#include <hip/hip_cooperative_groups.h>

namespace cg = cooperative_groups;

#define CDIV(a,b) (((a)+(b)-1)/(b))
#define NBUCK_MAX 512   // buckets of 128 nodes; supports N up to 65536 (ebuf packing needs N<=65536)
#define NTHR 256
#define SMEM_BYTES 32768

typedef __attribute__((ext_vector_type(8))) short short8;
typedef __attribute__((ext_vector_type(4))) float f32x4;

static __device__ __forceinline__ unsigned short f2bf(float f){
  union { float f; unsigned u; } v; v.f = f;
  unsigned r = v.u + 0x7fffu + ((v.u >> 16) & 1u);   // RNE
  return (unsigned short)(r >> 16);
}
static __device__ __forceinline__ unsigned pack2(float lo, float hi){
  return (unsigned)f2bf(lo) | ((unsigned)f2bf(hi) << 16);
}
static __device__ __forceinline__ float bfu_lo(unsigned u){
  union { unsigned u; float f; } v; v.u = u << 16; return v.f;
}
static __device__ __forceinline__ float bfu_hi(unsigned u){
  union { unsigned u; float f; } v; v.u = u & 0xffff0000u; return v.f;
}
static __device__ __forceinline__ float bf2f(unsigned short s){
  union { unsigned u; float f; } v; v.u = ((unsigned)s) << 16; return v.f;
}

#define ACC8(v) { a0 += bfu_lo(v.x); a1 += bfu_hi(v.x); a2 += bfu_lo(v.y); a3 += bfu_hi(v.y); \
                  a4 += bfu_lo(v.z); a5 += bfu_hi(v.z); a6 += bfu_lo(v.w); a7 += bfu_hi(v.w); }

// ---------------- weight pack ----------------

struct WtpArgs {
  const float *W0, *W1, *bl, *g, *b, *rm, *rv;
  unsigned short* Bpk; float *sc; float *sh;
  int kblk, dout, do_bn, tot;
};

static __device__ __forceinline__ void wtp_one(const WtpArgs& a, int idx){
  int NB16 = a.kblk*32*a.dout;
  if (idx < NB16){
    int j = idx & 7, lane = (idx >> 3) & 63, rest = idx >> 9;
    int NT = a.dout >> 4;
    int nt = rest % NT, kk = rest / NT;
    int nn = nt*16 + (lane & 15);
    int k  = kk*32 + ((lane >> 4) * 8) + j;
    float v = (k < 128) ? a.W0[nn*128 + k] : a.W1[nn*128 + (k - 128)];
    a.Bpk[idx] = f2bf(v);
  } else if (a.do_bn && idx < NB16 + a.dout){
    int jj = idx - NB16;
    float s = a.g[jj] * rsqrtf(a.rv[jj] + 1e-5f);
    a.sc[jj] = s;
    a.sh[jj] = (a.bl[jj] - a.rm[jj]) * s + a.b[jj];
  }
}

// ---------------- params ----------------

struct AP {
  const float* x;
  const int *esrc, *edst;
  int N, E, nbuck, ntiles, castN2, echunks;
  int *bcnt, *bcur, *bbase, *off, *csr;
  unsigned *ebuf, *xb, *mb, *h_a, *h_b, *ylb;
  const unsigned short *Bpk0, *Bpk1, *BpkL, *BpkR;
  const float *sc0,*sh0,*sc1,*sh1,*sc2,*sh2;
  WtpArgs wa0, wa1, wa2, wa3;
  float* out;
};

// ---------------- phase: prep (cast + histogram + weight pack) ----------------

static __device__ void ph_prep(const AP& P, unsigned char* smem){
  const int t = threadIdx.x;
  const int gsz = gridDim.x*NTHR;
  const int gtid = blockIdx.x*NTHR + t;
  for (int i = gtid; i < P.castN2; i += gsz){
    float2 v = ((const float2*)P.x)[i];
    P.xb[i] = pack2(v.x, v.y);
  }
  int* shist = (int*)smem;
  for (int i=t;i<P.nbuck;i+=NTHR) shist[i] = 0;
  __syncthreads();
  for (int e = gtid; e < P.E; e += gsz) atomicAdd(&shist[P.edst[e] >> 7], 1);
  __syncthreads();
  for (int i=t;i<P.nbuck;i+=NTHR){ int c = shist[i]; if (c) atomicAdd(&P.bcnt[i], c); }
  int tot0 = P.wa0.tot, tot1 = tot0 + P.wa1.tot, tot2 = tot1 + P.wa2.tot, tot3 = tot2 + P.wa3.tot;
  for (int i = gtid; i < tot3; i += gsz){
    if (i < tot0) wtp_one(P.wa0, i);
    else if (i < tot1) wtp_one(P.wa1, i - tot0);
    else if (i < tot2) wtp_one(P.wa2, i - tot1);
    else wtp_one(P.wa3, i - tot2);
  }
}

// ---------------- phase: bucket exclusive scan (single block) ----------------

static __device__ void ph_scan(const AP& P, unsigned char* smem){
  int* s = (int*)smem;
  const int t = threadIdx.x;
  int a0 = (2*t   < P.nbuck) ? P.bcnt[2*t]   : 0;
  int a1 = (2*t+1 < P.nbuck) ? P.bcnt[2*t+1] : 0;
  s[t] = a0 + a1; __syncthreads();
  for (int d=1; d<NTHR; d<<=1){
    int u = (t>=d) ? s[t-d] : 0;
    __syncthreads();
    s[t] += u;
    __syncthreads();
  }
  int excl = s[t] - (a0 + a1);
  if (2*t   < P.nbuck) P.bbase[2*t]   = excl;
  if (2*t+1 < P.nbuck) P.bbase[2*t+1] = excl + a0;
  if (t == NTHR-1) P.bbase[P.nbuck] = s[NTHR-1];
}

// ---------------- phase: bucketA ----------------

static __device__ void ph_bucketA(const AP& P, unsigned char* smem){
  int* scnt  = (int*)smem;
  int* sbase = scnt + NBUCK_MAX;
  int* sboff = sbase + NBUCK_MAX;
  const int t = threadIdx.x;
  for (int ch = blockIdx.x; ch < P.echunks; ch += gridDim.x){
    for (int i=t;i<P.nbuck;i+=NTHR) scnt[i] = 0;
    __syncthreads();
    constexpr int EPT = 16;
    int e0 = ch*NTHR*EPT;
    int b[EPT]; unsigned pk[EPT];
    #pragma unroll
    for (int i=0;i<EPT;i++){
      int e = e0 + i*NTHR + t;
      if (e < P.E){
        int d = P.edst[e];
        b[i] = d >> 7;
        pk[i] = ((unsigned)(d & 127) << 16) | (unsigned)P.esrc[e];
        atomicAdd(&scnt[b[i]], 1);
      } else b[i] = -1;
    }
    __syncthreads();
    for (int i=t;i<P.nbuck;i+=NTHR){
      int c = scnt[i];
      sbase[i] = (c > 0) ? atomicAdd(&P.bcur[i], c) : 0;
      sboff[i] = P.bbase[i];
      scnt[i] = 0;
    }
    __syncthreads();
    #pragma unroll
    for (int i=0;i<EPT;i++){
      if (b[i] >= 0){
        int p = atomicAdd(&scnt[b[i]], 1);
        P.ebuf[(size_t)sboff[b[i]] + sbase[b[i]] + p] = pk[i];
      }
    }
    __syncthreads();
  }
}

// ---------------- phase: bucketB ----------------

static __device__ void ph_bucketB(const AP& P, unsigned char* smem){
  int* sdeg = (int*)smem;
  int* sabs = sdeg + 128;
  int* cur  = sabs + 132;
  const int t = threadIdx.x;
  for (int b = blockIdx.x; b < P.nbuck; b += gridDim.x){
    int n0 = b << 7, n1 = min(n0 + 128, P.N);
    if (t < 128){ sdeg[t] = 0; cur[t] = 0; }
    __syncthreads();
    int e0 = P.bbase[b], e1 = P.bbase[b+1];
    for (int e = e0 + t; e < e1; e += NTHR)
      atomicAdd(&sdeg[P.ebuf[e] >> 16], 1);
    __syncthreads();
    for (int d=1; d<128; d<<=1){
      int u = (t < 128 && t >= d) ? sdeg[t-d] : 0;
      __syncthreads();
      if (t < 128) sdeg[t] += u;
      __syncthreads();
    }
    if (t == 0) sabs[0] = e0;
    if (t < 128) sabs[t+1] = e0 + sdeg[t];
    __syncthreads();
    if (t <= n1 - n0) P.off[n0 + t] = sabs[t];
    for (int e = e0 + t; e < e1; e += NTHR){
      unsigned pr = P.ebuf[e];
      int ln = (int)(pr >> 16);
      int p = atomicAdd(&cur[ln], 1);
      P.csr[sabs[ln] + p] = (int)(pr & 0xffffu);
    }
    __syncthreads();
  }
}

// ---------------- phase: mean aggregation, 128-dim rows ----------------

static __device__ void ph_agg128(const AP& P, const unsigned* hin, unsigned* mean){
  const uint4* hin4 = (const uint4*)hin;
  uint4* mean4 = (uint4*)mean;
  int t = threadIdx.x, lane = t & 63;
  int sl = lane & 15, quad = lane >> 4;
  int gw = blockIdx.x*4 + (t >> 6);
  int ngroups = (P.N + 3) >> 2;
  for (int g = gw; g < ngroups; g += gridDim.x*4){
    int node = g*4 + quad;
    bool valid = node < P.N;
    int s0 = valid ? P.off[node]   : 0;
    int s1 = valid ? P.off[node+1] : 0;
    float a0=0,a1=0,a2=0,a3=0,a4=0,a5=0,a6=0,a7=0;
    int e = s0;
    for (; e + 16 <= s1; e += 16){
      uint4 v[16];
      #pragma unroll
      for (int i=0;i<16;i++) v[i] = hin4[(size_t)P.csr[e+i]*16 + sl];
      #pragma unroll
      for (int i=0;i<16;i++) ACC8(v[i]);
    }
    for (; e + 4 <= s1; e += 4){
      uint4 v[4];
      #pragma unroll
      for (int i=0;i<4;i++) v[i] = hin4[(size_t)P.csr[e+i]*16 + sl];
      #pragma unroll
      for (int i=0;i<4;i++) ACC8(v[i]);
    }
    for (; e < s1; e++){
      uint4 v = hin4[(size_t)P.csr[e]*16 + sl];
      ACC8(v);
    }
    if (valid){
      int d = s1 - s0;
      float inv = 1.0f / (float)(d > 0 ? d : 1);
      uint4 o;
      o.x = pack2(a0*inv, a1*inv);
      o.y = pack2(a2*inv, a3*inv);
      o.z = pack2(a4*inv, a5*inv);
      o.w = pack2(a6*inv, a7*inv);
      mean4[(size_t)node*16 + sl] = o;
    }
  }
}

// ---------------- phase: hidden GEMM (B staged in two 32KB halves), optional fused yl ----------------

static __device__ void ph_gemm_hid(const AP& P, unsigned char* smem,
    const unsigned short* __restrict__ A0, const unsigned short* __restrict__ A1,
    const unsigned short* __restrict__ Bpk, const float* __restrict__ sc,
    const float* __restrict__ sh, const unsigned short* __restrict__ BpkL,
    unsigned short* __restrict__ outh, unsigned short* __restrict__ outyl, bool yl){
  unsigned short* Bs = (unsigned short*)smem;
  const int t = threadIdx.x;
  const int n = P.N;
  int lane = t & 63, w = t >> 6;
  int quad = lane >> 4, c = lane & 15;

  for (int tile = blockIdx.x; tile < P.ntiles; tile += gridDim.x){
    int mb = tile*128, woff = w*32;
    int r0 = mb + woff + c;
    int r1 = r0 + 16;

    f32x4 acc[2][8];
    #pragma unroll
    for (int mt=0;mt<2;mt++)
      #pragma unroll
      for (int nt=0;nt<8;nt++) acc[mt][nt] = (f32x4){0.f,0.f,0.f,0.f};

    // half 1: K=0..127, A = A0 (mean)
    {
      const uint4* s = (const uint4*)Bpk;
      uint4* d = (uint4*)Bs;
      #pragma unroll
      for (int i=0;i<8;i++) d[i*256 + t] = s[i*256 + t];
    }
    __syncthreads();
    #pragma unroll
    for (int kk=0; kk<4; kk++){
      int ka = kk*32 + quad*8;
      short8 a0 = {0,0,0,0,0,0,0,0}, a1 = {0,0,0,0,0,0,0,0};
      if (r0 < n) a0 = *(const short8*)(A0 + (size_t)r0*128 + ka);
      if (r1 < n) a1 = *(const short8*)(A0 + (size_t)r1*128 + ka);
      #pragma unroll
      for (int nt=0; nt<8; nt++){
        short8 b = *(const short8*)&Bs[(size_t)((kk*8 + nt)*64 + lane)*8];
        acc[0][nt] = __builtin_amdgcn_mfma_f32_16x16x32_bf16(a0, b, acc[0][nt], 0, 0, 0);
        acc[1][nt] = __builtin_amdgcn_mfma_f32_16x16x32_bf16(a1, b, acc[1][nt], 0, 0, 0);
      }
    }
    __syncthreads();
    // half 2: K=128..255, A = A1 (x/h)
    {
      const uint4* s = (const uint4*)(Bpk + 16384);
      uint4* d = (uint4*)Bs;
      #pragma unroll
      for (int i=0;i<8;i++) d[i*256 + t] = s[i*256 + t];
    }
    __syncthreads();
    #pragma unroll
    for (int kk=0; kk<4; kk++){
      int ka = kk*32 + quad*8;
      short8 a0 = {0,0,0,0,0,0,0,0}, a1 = {0,0,0,0,0,0,0,0};
      if (r0 < n) a0 = *(const short8*)(A1 + (size_t)r0*128 + ka);
      if (r1 < n) a1 = *(const short8*)(A1 + (size_t)r1*128 + ka);
      #pragma unroll
      for (int nt=0; nt<8; nt++){
        short8 b = *(const short8*)&Bs[(size_t)((kk*8 + nt)*64 + lane)*8];
        acc[0][nt] = __builtin_amdgcn_mfma_f32_16x16x32_bf16(a0, b, acc[0][nt], 0, 0, 0);
        acc[1][nt] = __builtin_amdgcn_mfma_f32_16x16x32_bf16(a1, b, acc[1][nt], 0, 0, 0);
      }
    }

    float scv[8], shv[8];
    #pragma unroll
    for (int nt=0;nt<8;nt++){ scv[nt] = sc[nt*16 + c]; shv[nt] = sh[nt*16 + c]; }

    #pragma unroll
    for (int mt=0; mt<2; mt++){
      #pragma unroll
      for (int r=0;r<4;r++){
        int row = mb + woff + mt*16 + quad*4 + r;
        if (row < n){
          #pragma unroll
          for (int nt=0;nt<8;nt++){
            float u = acc[mt][nt][r]*scv[nt] + shv[nt];
            u = fmaxf(u, 0.f);
            outh[(size_t)row*128 + nt*16 + c] = f2bf(u);
          }
        }
      }
    }

    if (yl){
      __syncthreads();   // drain outh stores + finish Bs reads
      {
        const uint4* sL = (const uint4*)BpkL;
        uint4* d = (uint4*)Bs;
        #pragma unroll
        for (int i=0;i<4;i++) d[i*256 + t] = sL[i*256 + t];
      }
      __syncthreads();
      f32x4 acc2[2][4];
      #pragma unroll
      for (int mt=0;mt<2;mt++)
        #pragma unroll
        for (int nt=0;nt<4;nt++) acc2[mt][nt] = (f32x4){0.f,0.f,0.f,0.f};
      int gr0 = r0 < n ? r0 : n-1;
      int gr1 = r1 < n ? r1 : n-1;
      #pragma unroll
      for (int kk=0; kk<4; kk++){
        int ka = kk*32 + quad*8;
        short8 a0 = *(const short8*)(outh + (size_t)gr0*128 + ka);
        short8 a1 = *(const short8*)(outh + (size_t)gr1*128 + ka);
        #pragma unroll
        for (int nt=0; nt<4; nt++){
          short8 b = *(const short8*)&Bs[(size_t)((kk*4 + nt)*64 + lane)*8];
          acc2[0][nt] = __builtin_amdgcn_mfma_f32_16x16x32_bf16(a0, b, acc2[0][nt], 0, 0, 0);
          acc2[1][nt] = __builtin_amdgcn_mfma_f32_16x16x32_bf16(a1, b, acc2[1][nt], 0, 0, 0);
        }
      }
      #pragma unroll
      for (int mt=0; mt<2; mt++){
        #pragma unroll
        for (int r=0;r<4;r++){
          int row = mb + woff + mt*16 + quad*4 + r;
          if (row < n){
            #pragma unroll
            for (int nt=0;nt<4;nt++) outyl[(size_t)row*64 + nt*16 + c] = f2bf(acc2[mt][nt][r]);
          }
        }
      }
    }
    __syncthreads();
  }
}

// ---------------- phase: fused layer-3 (mean-yl gather + GEMM + BN + L2norm) ----------------

static __device__ void ph_aggf(const AP& P, unsigned char* smem){
  const uint4* ylb4 = (const uint4*)P.ylb;
  const unsigned short* A0 = (const unsigned short*)P.h_b;
  unsigned short* Ms = (unsigned short*)smem;          // 16 KB
  unsigned short* Bs = Ms + 128*64;                    // 16 KB
  const int t = threadIdx.x;
  const int n = P.N;
  int lane = t & 63, w = t >> 6;
  int sl8 = lane & 7;
  int quad = lane >> 4, c = lane & 15;

  for (int tile = blockIdx.x; tile < P.ntiles; tile += gridDim.x){
    int mb = tile*128;
    {
      const uint4* s = (const uint4*)P.BpkR;
      uint4* d = (uint4*)Bs;
      #pragma unroll
      for (int i=0;i<4;i++) d[i*256 + t] = s[i*256 + t];
    }

    #pragma unroll
    for (int it=0; it<4; it++){
      int ln = w*32 + it*8 + (lane >> 3);
      int node = mb + ln;
      bool valid = node < n;
      int s0 = valid ? P.off[node]   : 0;
      int s1 = valid ? P.off[node+1] : 0;
      float a0=0,a1=0,a2=0,a3=0,a4=0,a5=0,a6=0,a7=0;
      int e = s0;
      for (; e + 4 <= s1; e += 4){
        uint4 v0 = ylb4[(size_t)P.csr[e  ]*8 + sl8];
        uint4 v1 = ylb4[(size_t)P.csr[e+1]*8 + sl8];
        uint4 v2 = ylb4[(size_t)P.csr[e+2]*8 + sl8];
        uint4 v3 = ylb4[(size_t)P.csr[e+3]*8 + sl8];
        ACC8(v0); ACC8(v1); ACC8(v2); ACC8(v3);
      }
      for (; e < s1; e++){
        uint4 v = ylb4[(size_t)P.csr[e]*8 + sl8];
        ACC8(v);
      }
      int d = s1 - s0;
      float inv = 1.0f / (float)(d > 0 ? d : 1);
      uint4 o;
      o.x = pack2(a0*inv, a1*inv);
      o.y = pack2(a2*inv, a3*inv);
      o.z = pack2(a4*inv, a5*inv);
      o.w = pack2(a6*inv, a7*inv);
      ((uint4*)Ms)[ln*8 + sl8] = o;
    }
    __syncthreads();

    int woff = w*32;
    int r0 = mb + woff + c;
    int r1 = r0 + 16;
    f32x4 acc[2][4];
    #pragma unroll
    for (int mt=0;mt<2;mt++)
      #pragma unroll
      for (int nt=0;nt<4;nt++) acc[mt][nt] = (f32x4){0.f,0.f,0.f,0.f};
    #pragma unroll
    for (int kk=0; kk<4; kk++){
      int ka = kk*32 + quad*8;
      short8 a0 = {0,0,0,0,0,0,0,0}, a1 = {0,0,0,0,0,0,0,0};
      if (r0 < n) a0 = *(const short8*)(A0 + (size_t)r0*128 + ka);
      if (r1 < n) a1 = *(const short8*)(A0 + (size_t)r1*128 + ka);
      #pragma unroll
      for (int nt=0; nt<4; nt++){
        short8 b = *(const short8*)&Bs[(size_t)((kk*4 + nt)*64 + lane)*8];
        acc[0][nt] = __builtin_amdgcn_mfma_f32_16x16x32_bf16(a0, b, acc[0][nt], 0, 0, 0);
        acc[1][nt] = __builtin_amdgcn_mfma_f32_16x16x32_bf16(a1, b, acc[1][nt], 0, 0, 0);
      }
    }

    float scv[4], shv[4];
    #pragma unroll
    for (int nt=0;nt<4;nt++){ scv[nt] = P.sc2[nt*16 + c]; shv[nt] = P.sh2[nt*16 + c]; }

    #pragma unroll
    for (int mt=0; mt<2; mt++){
      #pragma unroll
      for (int r=0;r<4;r++){
        int lr = woff + mt*16 + quad*4 + r;
        int row = mb + lr;
        float v[4];
        float ss = 0.f;
        if (row < n){
          #pragma unroll
          for (int nt=0;nt<4;nt++){
            float u = acc[mt][nt][r] + bf2f(Ms[lr*64 + nt*16 + c]);
            u = u*scv[nt] + shv[nt];
            v[nt] = u;
            ss += u*u;
          }
        } else {
          #pragma unroll
          for (int nt=0;nt<4;nt++) v[nt] = 0.f;
        }
        ss += __shfl_xor(ss, 1, 64);
        ss += __shfl_xor(ss, 2, 64);
        ss += __shfl_xor(ss, 4, 64);
        ss += __shfl_xor(ss, 8, 64);
        float rn = 1.0f / fmaxf(sqrtf(ss), 1e-12f);
        if (row < n){
          #pragma unroll
          for (int nt=0;nt<4;nt++) P.out[(size_t)row*64 + nt*16 + c] = v[nt]*rn;
        }
      }
    }
    __syncthreads();
  }
}

// ---------------- cooperative mega-kernel ----------------

__global__ __launch_bounds__(NTHR, 2) void k_all(AP P){
  cg::grid_group grid = cg::this_grid();
  __shared__ __align__(16) unsigned char smem[SMEM_BYTES];
  ph_prep(P, smem);
  grid.sync();
  if (blockIdx.x == 0) ph_scan(P, smem);
  grid.sync();
  ph_bucketA(P, smem);
  grid.sync();
  ph_bucketB(P, smem);
  grid.sync();
  ph_agg128(P, P.xb, P.mb);
  grid.sync();
  ph_gemm_hid(P, smem, (const unsigned short*)P.mb, (const unsigned short*)P.xb,
              P.Bpk0, P.sc0, P.sh0, nullptr, (unsigned short*)P.h_a, nullptr, false);
  grid.sync();
  ph_agg128(P, P.h_a, P.mb);
  grid.sync();
  ph_gemm_hid(P, smem, (const unsigned short*)P.mb, (const unsigned short*)P.h_a,
              P.Bpk1, P.sc1, P.sh1, P.BpkL, (unsigned short*)P.h_b, (unsigned short*)P.ylb, true);
  grid.sync();
  ph_aggf(P, smem);
}

// ---------------- standalone fallback kernels (same device functions) ----------------

__global__ __launch_bounds__(NTHR) void k_s_prep(AP P){
  __shared__ __align__(16) unsigned char smem[SMEM_BYTES];
  ph_prep(P, smem);
}
__global__ __launch_bounds__(NTHR) void k_s_scan(AP P){
  __shared__ __align__(16) unsigned char smem[4096];
  ph_scan(P, smem);
}
__global__ __launch_bounds__(NTHR) void k_s_bA(AP P){
  __shared__ __align__(16) unsigned char smem[NBUCK_MAX*3*4];
  ph_bucketA(P, smem);
}
__global__ __launch_bounds__(NTHR) void k_s_bB(AP P){
  __shared__ __align__(16) unsigned char smem[4096];
  ph_bucketB(P, smem);
}
__global__ __launch_bounds__(NTHR) void k_s_agg(AP P, const unsigned* hin, unsigned* mean){
  ph_agg128(P, hin, mean);
}
__global__ __launch_bounds__(NTHR, 2) void k_s_gemm0(AP P){
  __shared__ __align__(16) unsigned char smem[SMEM_BYTES];
  ph_gemm_hid(P, smem, (const unsigned short*)P.mb, (const unsigned short*)P.xb,
              P.Bpk0, P.sc0, P.sh0, nullptr, (unsigned short*)P.h_a, nullptr, false);
}
__global__ __launch_bounds__(NTHR, 2) void k_s_gemm1(AP P){
  __shared__ __align__(16) unsigned char smem[SMEM_BYTES];
  ph_gemm_hid(P, smem, (const unsigned short*)P.mb, (const unsigned short*)P.h_a,
              P.Bpk1, P.sc1, P.sh1, P.BpkL, (unsigned short*)P.h_b, (unsigned short*)P.ylb, true);
}
__global__ __launch_bounds__(NTHR, 2) void k_s_aggf(AP P){
  __shared__ __align__(16) unsigned char smem[SMEM_BYTES];
  ph_aggf(P, smem);
}

// ---------------- launcher ----------------

extern "C" void kernel_launch(void* const* d_in, const int* in_sizes, int n_in,
                              void* d_out, int out_size, void* d_ws, size_t ws_size,
                              hipStream_t stream){
  const float* x = (const float*)d_in[0];
  const int* ei  = (const int*)d_in[1];
  int N = in_sizes[0] / 128;
  int E = in_sizes[1] / 2;
  int nbuck = CDIV(N, 128);

  const float *Wl[3], *bl[3], *Wr[3], *g[3], *bb[3], *rm[3], *rv[3];
  int dout[3];
  for (int i=0;i<3;i++){
    int base = 2 + 7*i;
    Wl[i]=(const float*)d_in[base];   bl[i]=(const float*)d_in[base+1];
    Wr[i]=(const float*)d_in[base+2]; g[i] =(const float*)d_in[base+3];
    bb[i]=(const float*)d_in[base+4]; rm[i]=(const float*)d_in[base+5];
    rv[i]=(const float*)d_in[base+6];
    dout[i] = in_sizes[base] / 128;
  }

  char* p = (char*)d_ws;
  size_t o = 0;
  auto alloc = [&](size_t bytes)->void*{ void* r = p + o; o += (bytes + 255) & ~(size_t)255; return r; };
  int* bz    = (int*)alloc((size_t)2*nbuck*4);
  int* bcnt  = bz;
  int* bcur  = bz + nbuck;
  int* bbase = (int*)alloc((size_t)(nbuck+1)*4);
  int* off   = (int*)alloc((size_t)(N+1)*4);
  int* csr   = (int*)alloc((size_t)E*4);
  unsigned* ebuf = (unsigned*)alloc((size_t)E*4);
  unsigned* xb   = (unsigned*)alloc((size_t)N*64*4);
  unsigned* mb   = (unsigned*)alloc((size_t)N*64*4);
  unsigned* h_a  = (unsigned*)alloc((size_t)N*64*4);
  unsigned* h_b  = (unsigned*)alloc((size_t)N*64*4);
  unsigned* ylb  = (unsigned*)alloc((size_t)N*32*4);
  unsigned short* Bpk0 = (unsigned short*)alloc((size_t)256*dout[0]*2);
  unsigned short* Bpk1 = (unsigned short*)alloc((size_t)256*dout[1]*2);
  unsigned short* BpkL = (unsigned short*)alloc((size_t)128*dout[2]*2);
  unsigned short* BpkR = (unsigned short*)alloc((size_t)128*dout[2]*2);
  float* sc[3]; float* sh[3];
  for (int i=0;i<3;i++){
    sc[i] = (float*)alloc((size_t)dout[i]*4);
    sh[i] = (float*)alloc((size_t)dout[i]*4);
  }

  hipMemsetAsync(bz, 0, (size_t)2*nbuck*4, stream);

  AP ap;
  ap.x = x; ap.esrc = ei; ap.edst = ei + E;
  ap.N = N; ap.E = E; ap.nbuck = nbuck;
  ap.ntiles = CDIV(N, 128);
  ap.castN2 = N*64;
  ap.echunks = CDIV(E, NTHR*16);
  ap.bcnt = bcnt; ap.bcur = bcur; ap.bbase = bbase; ap.off = off; ap.csr = csr;
  ap.ebuf = ebuf; ap.xb = xb; ap.mb = mb; ap.h_a = h_a; ap.h_b = h_b; ap.ylb = ylb;
  ap.Bpk0 = Bpk0; ap.Bpk1 = Bpk1; ap.BpkL = BpkL; ap.BpkR = BpkR;
  ap.sc0 = sc[0]; ap.sh0 = sh[0]; ap.sc1 = sc[1]; ap.sh1 = sh[1]; ap.sc2 = sc[2]; ap.sh2 = sh[2];
  ap.wa0 = { Wl[0], Wr[0], bl[0], g[0], bb[0], rm[0], rv[0], Bpk0, sc[0], sh[0], 8, dout[0], 1, 256*dout[0] + dout[0] };
  ap.wa1 = { Wl[1], Wr[1], bl[1], g[1], bb[1], rm[1], rv[1], Bpk1, sc[1], sh[1], 8, dout[1], 1, 256*dout[1] + dout[1] };
  ap.wa2 = { Wl[2], nullptr, nullptr, nullptr, nullptr, nullptr, nullptr, BpkL, nullptr, nullptr, 4, dout[2], 0, 128*dout[2] };
  ap.wa3 = { Wr[2], nullptr, bl[2], g[2], bb[2], rm[2], rv[2], BpkR, sc[2], sh[2], 4, dout[2], 1, 128*dout[2] + dout[2] };
  ap.out = (float*)d_out;

  // try cooperative mega-kernel; clamp grid to queried occupancy; fall back on failure
  int nb = 0;
  hipError_t qerr = hipOccupancyMaxActiveBlocksPerMultiprocessor(&nb, (const void*)k_all, NTHR, 0);
  hipError_t lerr = hipErrorUnknown;
  if (qerr == hipSuccess && nb > 0){
    int grid = nb * 256;             // 256 CUs on MI355X
    if (grid > 512) grid = 512;
    if (grid >= 64){
      void* args[] = { (void*)&ap };
      lerr = hipLaunchCooperativeKernel((const void*)k_all, dim3(grid), dim3(NTHR), args, 0, stream);
    }
  }
  if (lerr != hipSuccess){
    (void)hipGetLastError();   // clear error state
    k_s_prep<<<512,NTHR,0,stream>>>(ap);
    k_s_scan<<<1,NTHR,0,stream>>>(ap);
    k_s_bA  <<<ap.echunks,NTHR,0,stream>>>(ap);
    k_s_bB  <<<ap.nbuck,NTHR,0,stream>>>(ap);
    k_s_agg <<<CDIV(CDIV(N,4),4),NTHR,0,stream>>>(ap, xb, mb);
    k_s_gemm0<<<ap.ntiles,NTHR,0,stream>>>(ap);
    k_s_agg <<<CDIV(CDIV(N,4),4),NTHR,0,stream>>>(ap, h_a, mb);
    k_s_gemm1<<<ap.ntiles,NTHR,0,stream>>>(ap);
    k_s_aggf<<<ap.ntiles,NTHR,0,stream>>>(ap);
  }
}

// Round 9
// 270.479 us; speedup vs baseline: 2.4341x; 2.4341x over previous
//
#include <hip/hip_runtime.h>
#include <hip/hip_bf16.h>

#define CDIV(a,b) (((a)+(b)-1)/(b))
#define NBUCK_MAX 512   // buckets of 128 nodes; supports N up to 65536 (ebuf packing needs N<=65536)

typedef __attribute__((ext_vector_type(8))) short short8;
typedef __attribute__((ext_vector_type(4))) float f32x4;

static __device__ __forceinline__ unsigned short f2bf(float f){
  union { float f; unsigned u; } v; v.f = f;
  unsigned r = v.u + 0x7fffu + ((v.u >> 16) & 1u);   // RNE
  return (unsigned short)(r >> 16);
}
static __device__ __forceinline__ unsigned pack2(float lo, float hi){
  return (unsigned)f2bf(lo) | ((unsigned)f2bf(hi) << 16);
}
static __device__ __forceinline__ float bfu_lo(unsigned u){
  union { unsigned u; float f; } v; v.u = u << 16; return v.f;
}
static __device__ __forceinline__ float bfu_hi(unsigned u){
  union { unsigned u; float f; } v; v.u = u & 0xffff0000u; return v.f;
}
static __device__ __forceinline__ float bf2f(unsigned short s){
  union { unsigned u; float f; } v; v.u = ((unsigned)s) << 16; return v.f;
}

#define ACC8(v) { a0 += bfu_lo(v.x); a1 += bfu_hi(v.x); a2 += bfu_lo(v.y); a3 += bfu_hi(v.y); \
                  a4 += bfu_lo(v.z); a5 += bfu_hi(v.z); a6 += bfu_lo(v.w); a7 += bfu_hi(v.w); }

// ---------------- weight pack ----------------

struct WtpArgs {
  const float *W0, *W1, *bl, *g, *b, *rm, *rv;
  unsigned short* Bpk; float *sc; float *sh;
  int kblk, dout, do_bn, nblk;
};

static __device__ __forceinline__ void wtp_one(const WtpArgs& a, int idx){
  int NB16 = a.kblk*32*a.dout;
  if (idx < NB16){
    int j = idx & 7, lane = (idx >> 3) & 63, rest = idx >> 9;
    int NT = a.dout >> 4;
    int nt = rest % NT, kk = rest / NT;
    int nn = nt*16 + (lane & 15);
    int k  = kk*32 + ((lane >> 4) * 8) + j;
    float v = (k < 128) ? a.W0[nn*128 + k] : a.W1[nn*128 + (k - 128)];
    a.Bpk[idx] = f2bf(v);
  } else if (a.do_bn && idx < NB16 + a.dout){
    int jj = idx - NB16;
    float s = a.g[jj] * rsqrtf(a.rv[jj] + 1e-5f);
    a.sc[jj] = s;
    a.sh[jj] = (a.bl[jj] - a.rm[jj]) * s + a.b[jj];
  }
}

// ---------------- prep: cast x->bf16 | bucket histogram | weight pack, one launch ----------------

__global__ __launch_bounds__(256) void k_prep(const float* __restrict__ x, int n2, unsigned* __restrict__ xb,
                                              const int* __restrict__ dst, int E,
                                              int* __restrict__ bcnt, int nbuck,
                                              int castBlocks, int histBlocks,
                                              WtpArgs a0, WtpArgs a1, WtpArgs a2, WtpArgs a3){
  __shared__ int s[NBUCK_MAX];
  int b = blockIdx.x, t = threadIdx.x;
  if (b < castBlocks){
    int i = b*256 + t;
    if (i < n2){
      float2 v = ((const float2*)x)[i];
      xb[i] = pack2(v.x, v.y);
    }
    return;
  }
  b -= castBlocks;
  if (b < histBlocks){
    for (int i=t;i<nbuck;i+=256) s[i] = 0;
    __syncthreads();
    constexpr int EPT = 16;
    int e0 = b*256*EPT;
    #pragma unroll
    for (int i=0;i<EPT;i++){
      int e = e0 + i*256 + t;
      if (e < E) atomicAdd(&s[dst[e] >> 7], 1);
    }
    __syncthreads();
    for (int i=t;i<nbuck;i+=256){
      int c = s[i];
      if (c > 0) atomicAdd(&bcnt[i], c);
    }
    return;
  }
  b -= histBlocks;
  if (b < a0.nblk){ wtp_one(a0, b*256 + t); return; }
  b -= a0.nblk;
  if (b < a1.nblk){ wtp_one(a1, b*256 + t); return; }
  b -= a1.nblk;
  if (b < a2.nblk){ wtp_one(a2, b*256 + t); return; }
  b -= a2.nblk;
  wtp_one(a3, b*256 + t);
}

// single block: exclusive scan of bcnt[0..nbuck) -> bbase[0..nbuck], bbase[nbuck]=E
__global__ __launch_bounds__(256) void k_bscan(const int* __restrict__ bcnt, int nbuck,
                                               int* __restrict__ bbase){
  __shared__ int s[256];
  int t = threadIdx.x;
  int a0 = (2*t   < nbuck) ? bcnt[2*t]   : 0;
  int a1 = (2*t+1 < nbuck) ? bcnt[2*t+1] : 0;
  s[t] = a0 + a1; __syncthreads();
  for (int d=1; d<256; d<<=1){
    int u = (t>=d) ? s[t-d] : 0;
    __syncthreads();
    s[t] += u;
    __syncthreads();
  }
  int excl = s[t] - (a0 + a1);
  if (2*t   < nbuck) bbase[2*t]   = excl;
  if (2*t+1 < nbuck) bbase[2*t+1] = excl + a0;
  if (t == 255) bbase[nbuck] = s[255];
}

// Pass A: bin edges into 128-node buckets; packed entry (local_dst<<16)|src (N<=65536)
__global__ __launch_bounds__(256) void k_bucketA(const int* __restrict__ src, const int* __restrict__ dst,
                                                 int E, const int* __restrict__ bbase,
                                                 int* __restrict__ bcur, unsigned* __restrict__ ebuf, int nbuck){
  __shared__ int scnt[NBUCK_MAX];
  __shared__ int sbase[NBUCK_MAX];
  __shared__ int sboff[NBUCK_MAX];
  int t = threadIdx.x;
  for (int i=t;i<nbuck;i+=256) scnt[i] = 0;
  __syncthreads();
  constexpr int EPT = 16;
  int e0 = blockIdx.x*256*EPT;
  int b[EPT]; unsigned pk[EPT];
  #pragma unroll
  for (int i=0;i<EPT;i++){
    int e = e0 + i*256 + t;
    if (e < E){
      int d = dst[e];
      b[i] = d >> 7;
      pk[i] = ((unsigned)(d & 127) << 16) | (unsigned)src[e];
      atomicAdd(&scnt[b[i]], 1);
    } else b[i] = -1;
  }
  __syncthreads();
  for (int i=t;i<nbuck;i+=256){
    int c = scnt[i];
    sbase[i] = (c > 0) ? atomicAdd(&bcur[i], c) : 0;
    sboff[i] = bbase[i];
    scnt[i] = 0;
  }
  __syncthreads();
  #pragma unroll
  for (int i=0;i<EPT;i++){
    if (b[i] >= 0){
      int p = atomicAdd(&scnt[b[i]], 1);
      ebuf[(size_t)sboff[b[i]] + sbase[b[i]] + p] = pk[i];
    }
  }
}

// Pass B: one block per bucket; local degree count + scan -> off + csr scatter in ~8KB window.
__global__ __launch_bounds__(256) void k_bucketB(const unsigned* __restrict__ ebuf, const int* __restrict__ bbase,
                                                 int N, int* __restrict__ off, int* __restrict__ csr){
  int b = blockIdx.x;
  int n0 = b << 7, n1 = min(n0 + 128, N);
  __shared__ int sdeg[128];
  __shared__ int sabs[129];
  __shared__ int cur[128];
  int t = threadIdx.x;
  if (t < 128){ sdeg[t] = 0; cur[t] = 0; }
  __syncthreads();
  int e0 = bbase[b], e1 = bbase[b+1];
  for (int e = e0 + t; e < e1; e += 256)
    atomicAdd(&sdeg[ebuf[e] >> 16], 1);
  __syncthreads();
  for (int d=1; d<128; d<<=1){
    int u = (t < 128 && t >= d) ? sdeg[t-d] : 0;
    __syncthreads();
    if (t < 128) sdeg[t] += u;
    __syncthreads();
  }
  if (t == 0) sabs[0] = e0;
  if (t < 128) sabs[t+1] = e0 + sdeg[t];
  __syncthreads();
  if (t <= n1 - n0) off[n0 + t] = sabs[t];
  for (int e = e0 + t; e < e1; e += 256){
    unsigned pr = ebuf[e];
    int ln = (int)(pr >> 16);
    int p = atomicAdd(&cur[ln], 1);
    csr[sabs[ln] + p] = (int)(pr & 0xffffu);
  }
}

// ---------------- mean aggregation, 128-dim rows: 4 nodes/wave, 16-deep gather pipeline ----------------

__global__ __launch_bounds__(256) void k_agg(const uint4* __restrict__ hin4, const int* __restrict__ off,
                                             const int* __restrict__ csr, int n, uint4* __restrict__ mean4){
  int tid = blockIdx.x*256 + threadIdx.x;
  int lane = threadIdx.x & 63;
  int sl = lane & 15;
  int node = (tid >> 6)*4 + (lane >> 4);
  bool valid = node < n;
  int s0 = valid ? off[node]   : 0;
  int s1 = valid ? off[node+1] : 0;
  float a0=0,a1=0,a2=0,a3=0,a4=0,a5=0,a6=0,a7=0;
  int e = s0;
  for (; e + 16 <= s1; e += 16){
    uint4 v[16];
    #pragma unroll
    for (int i=0;i<16;i++) v[i] = hin4[(size_t)csr[e+i]*16 + sl];
    #pragma unroll
    for (int i=0;i<16;i++) ACC8(v[i]);
  }
  for (; e + 4 <= s1; e += 4){
    uint4 v[4];
    #pragma unroll
    for (int i=0;i<4;i++) v[i] = hin4[(size_t)csr[e+i]*16 + sl];
    #pragma unroll
    for (int i=0;i<4;i++) ACC8(v[i]);
  }
  for (; e < s1; e++){
    uint4 v = hin4[(size_t)csr[e]*16 + sl];
    ACC8(v);
  }
  if (valid){
    int d = s1 - s0;
    float inv = 1.0f / (float)(d > 0 ? d : 1);
    uint4 o;
    o.x = pack2(a0*inv, a1*inv);
    o.y = pack2(a2*inv, a3*inv);
    o.z = pack2(a4*inv, a5*inv);
    o.w = pack2(a6*inv, a7*inv);
    mean4[(size_t)node*16 + sl] = o;
  }
}

// ---------------- hidden GEMM: 64-row tile, B staged in two 32KB halves, optional fused yl ----------------
// C[N][128] = [A0|A1]@B (K=256), BN+ReLU, bf16 out. If YL: yl = C@Wl2^T (K=128, DOUT=64) -> outyl
// (A for yl read back from outh global — same block wrote those rows; verified correct in r8).

template<bool YL>
__global__ __launch_bounds__(256, 4) void k_gemm_hid(
    const unsigned short* __restrict__ A0, const unsigned short* __restrict__ A1,
    const unsigned short* __restrict__ Bpk, const float* __restrict__ sc,
    const float* __restrict__ sh, const unsigned short* __restrict__ BpkL,
    unsigned short* __restrict__ outh, unsigned short* __restrict__ outyl, int n){
  __shared__ unsigned short Bs[128*128];   // 32 KB
  int t = threadIdx.x;
  int lane = t & 63, w = t >> 6;
  int quad = lane >> 4, c = lane & 15;
  int mb = blockIdx.x*64;
  int r0 = mb + w*16 + c;

  f32x4 acc[8];
  #pragma unroll
  for (int nt=0;nt<8;nt++) acc[nt] = (f32x4){0.f,0.f,0.f,0.f};

  // half 1: K=0..127, A = A0 (mean)
  {
    const uint4* s = (const uint4*)Bpk;
    uint4* d = (uint4*)Bs;
    #pragma unroll
    for (int i=0;i<8;i++) d[i*256 + t] = s[i*256 + t];
  }
  __syncthreads();
  #pragma unroll
  for (int kk=0; kk<4; kk++){
    int ka = kk*32 + quad*8;
    short8 a0 = {0,0,0,0,0,0,0,0};
    if (r0 < n) a0 = *(const short8*)(A0 + (size_t)r0*128 + ka);
    #pragma unroll
    for (int nt=0; nt<8; nt++){
      short8 b = *(const short8*)&Bs[(size_t)((kk*8 + nt)*64 + lane)*8];
      acc[nt] = __builtin_amdgcn_mfma_f32_16x16x32_bf16(a0, b, acc[nt], 0, 0, 0);
    }
  }
  __syncthreads();
  // half 2: K=128..255, A = A1 (x/h)
  {
    const uint4* s = (const uint4*)(Bpk + 16384);
    uint4* d = (uint4*)Bs;
    #pragma unroll
    for (int i=0;i<8;i++) d[i*256 + t] = s[i*256 + t];
  }
  __syncthreads();
  #pragma unroll
  for (int kk=0; kk<4; kk++){
    int ka = kk*32 + quad*8;
    short8 a0 = {0,0,0,0,0,0,0,0};
    if (r0 < n) a0 = *(const short8*)(A1 + (size_t)r0*128 + ka);
    #pragma unroll
    for (int nt=0; nt<8; nt++){
      short8 b = *(const short8*)&Bs[(size_t)((kk*8 + nt)*64 + lane)*8];
      acc[nt] = __builtin_amdgcn_mfma_f32_16x16x32_bf16(a0, b, acc[nt], 0, 0, 0);
    }
  }

  float scv[8], shv[8];
  #pragma unroll
  for (int nt=0;nt<8;nt++){ scv[nt] = sc[nt*16 + c]; shv[nt] = sh[nt*16 + c]; }

  #pragma unroll
  for (int r=0;r<4;r++){
    int row = mb + w*16 + quad*4 + r;
    if (row < n){
      #pragma unroll
      for (int nt=0;nt<8;nt++){
        float u = acc[nt][r]*scv[nt] + shv[nt];
        u = fmaxf(u, 0.f);
        outh[(size_t)row*128 + nt*16 + c] = f2bf(u);
      }
    }
  }

  if constexpr (YL){
    __syncthreads();   // drain outh stores + finish Bs reads
    {
      const uint4* sL = (const uint4*)BpkL;
      uint4* d = (uint4*)Bs;
      #pragma unroll
      for (int i=0;i<4;i++) d[i*256 + t] = sL[i*256 + t];
    }
    __syncthreads();
    f32x4 acc2[4];
    #pragma unroll
    for (int nt=0;nt<4;nt++) acc2[nt] = (f32x4){0.f,0.f,0.f,0.f};
    int gr0 = r0 < n ? r0 : n-1;
    #pragma unroll
    for (int kk=0; kk<4; kk++){
      int ka = kk*32 + quad*8;
      short8 a0 = *(const short8*)(outh + (size_t)gr0*128 + ka);
      #pragma unroll
      for (int nt=0; nt<4; nt++){
        short8 b = *(const short8*)&Bs[(size_t)((kk*4 + nt)*64 + lane)*8];
        acc2[nt] = __builtin_amdgcn_mfma_f32_16x16x32_bf16(a0, b, acc2[nt], 0, 0, 0);
      }
    }
    #pragma unroll
    for (int r=0;r<4;r++){
      int row = mb + w*16 + quad*4 + r;
      if (row < n){
        #pragma unroll
        for (int nt=0;nt<4;nt++) outyl[(size_t)row*64 + nt*16 + c] = f2bf(acc2[nt][r]);
      }
    }
  }
}

// ---------------- fused layer-3: 64-row tile, mean-yl gather + GEMM + BN + L2norm ----------------

__global__ __launch_bounds__(256, 4) void k_aggf(
    const uint4* __restrict__ ylb4, const int* __restrict__ off, const int* __restrict__ csr,
    const unsigned short* __restrict__ A0, const unsigned short* __restrict__ BpkR,
    const float* __restrict__ sc, const float* __restrict__ sh,
    float* __restrict__ outf, int n){
  __shared__ unsigned short Ms[64*64];     // 8 KB mean-yl tile
  __shared__ unsigned short Bs[128*64];    // 16 KB BpkR
  int t = threadIdx.x;
  int lane = t & 63, w = t >> 6;
  int mb = blockIdx.x*64;
  int sl8 = lane & 7;
  {
    const uint4* s = (const uint4*)BpkR;
    uint4* d = (uint4*)Bs;
    #pragma unroll
    for (int i=0;i<4;i++) d[i*256 + t] = s[i*256 + t];
  }

  // gather: wave w covers local rows [w*16, w*16+16), 8 nodes at a time
  #pragma unroll
  for (int it=0; it<2; it++){
    int ln = w*16 + it*8 + (lane >> 3);
    int node = mb + ln;
    bool valid = node < n;
    int s0 = valid ? off[node]   : 0;
    int s1 = valid ? off[node+1] : 0;
    float a0=0,a1=0,a2=0,a3=0,a4=0,a5=0,a6=0,a7=0;
    int e = s0;
    for (; e + 4 <= s1; e += 4){
      uint4 v0 = ylb4[(size_t)csr[e  ]*8 + sl8];
      uint4 v1 = ylb4[(size_t)csr[e+1]*8 + sl8];
      uint4 v2 = ylb4[(size_t)csr[e+2]*8 + sl8];
      uint4 v3 = ylb4[(size_t)csr[e+3]*8 + sl8];
      ACC8(v0); ACC8(v1); ACC8(v2); ACC8(v3);
    }
    for (; e < s1; e++){
      uint4 v = ylb4[(size_t)csr[e]*8 + sl8];
      ACC8(v);
    }
    int d = s1 - s0;
    float inv = 1.0f / (float)(d > 0 ? d : 1);
    uint4 o;
    o.x = pack2(a0*inv, a1*inv);
    o.y = pack2(a2*inv, a3*inv);
    o.z = pack2(a4*inv, a5*inv);
    o.w = pack2(a6*inv, a7*inv);
    ((uint4*)Ms)[ln*8 + sl8] = o;
  }
  __syncthreads();

  // GEMM: C = h_b @ Wr2^T (K=128), + mean-yl, BN, L2-normalize
  int quad = lane >> 4, c = lane & 15;
  int r0 = mb + w*16 + c;
  f32x4 acc[4];
  #pragma unroll
  for (int nt=0;nt<4;nt++) acc[nt] = (f32x4){0.f,0.f,0.f,0.f};
  #pragma unroll
  for (int kk=0; kk<4; kk++){
    int ka = kk*32 + quad*8;
    short8 a0 = {0,0,0,0,0,0,0,0};
    if (r0 < n) a0 = *(const short8*)(A0 + (size_t)r0*128 + ka);
    #pragma unroll
    for (int nt=0; nt<4; nt++){
      short8 b = *(const short8*)&Bs[(size_t)((kk*4 + nt)*64 + lane)*8];
      acc[nt] = __builtin_amdgcn_mfma_f32_16x16x32_bf16(a0, b, acc[nt], 0, 0, 0);
    }
  }

  float scv[4], shv[4];
  #pragma unroll
  for (int nt=0;nt<4;nt++){ scv[nt] = sc[nt*16 + c]; shv[nt] = sh[nt*16 + c]; }

  #pragma unroll
  for (int r=0;r<4;r++){
    int lr = w*16 + quad*4 + r;
    int row = mb + lr;
    float v[4];
    float ss = 0.f;
    if (row < n){
      #pragma unroll
      for (int nt=0;nt<4;nt++){
        float u = acc[nt][r] + bf2f(Ms[lr*64 + nt*16 + c]);
        u = u*scv[nt] + shv[nt];
        v[nt] = u;
        ss += u*u;
      }
    } else {
      #pragma unroll
      for (int nt=0;nt<4;nt++) v[nt] = 0.f;
    }
    ss += __shfl_xor(ss, 1, 64);
    ss += __shfl_xor(ss, 2, 64);
    ss += __shfl_xor(ss, 4, 64);
    ss += __shfl_xor(ss, 8, 64);
    float rn = 1.0f / fmaxf(sqrtf(ss), 1e-12f);
    if (row < n){
      #pragma unroll
      for (int nt=0;nt<4;nt++) outf[(size_t)row*64 + nt*16 + c] = v[nt]*rn;
    }
  }
}

// ---------------- launcher ----------------

extern "C" void kernel_launch(void* const* d_in, const int* in_sizes, int n_in,
                              void* d_out, int out_size, void* d_ws, size_t ws_size,
                              hipStream_t stream){
  const float* x = (const float*)d_in[0];
  const int* ei  = (const int*)d_in[1];
  int N = in_sizes[0] / 128;
  int E = in_sizes[1] / 2;
  const int* esrc = ei;
  const int* edst = ei + E;
  int nbuck = CDIV(N, 128);

  const float *Wl[3], *bl[3], *Wr[3], *g[3], *bb[3], *rm[3], *rv[3];
  int dout[3];
  for (int i=0;i<3;i++){
    int base = 2 + 7*i;
    Wl[i]=(const float*)d_in[base];   bl[i]=(const float*)d_in[base+1];
    Wr[i]=(const float*)d_in[base+2]; g[i] =(const float*)d_in[base+3];
    bb[i]=(const float*)d_in[base+4]; rm[i]=(const float*)d_in[base+5];
    rv[i]=(const float*)d_in[base+6];
    dout[i] = in_sizes[base] / 128;
  }

  char* p = (char*)d_ws;
  size_t o = 0;
  auto alloc = [&](size_t bytes)->void*{ void* r = p + o; o += (bytes + 255) & ~(size_t)255; return r; };
  int* bz    = (int*)alloc((size_t)2*nbuck*4);   // bcnt | bcur (one memset)
  int* bcnt  = bz;
  int* bcur  = bz + nbuck;
  int* bbase = (int*)alloc((size_t)(nbuck+1)*4);
  int* off   = (int*)alloc((size_t)(N+1)*4);
  int* csr   = (int*)alloc((size_t)E*4);
  unsigned* ebuf = (unsigned*)alloc((size_t)E*4);
  unsigned* xb   = (unsigned*)alloc((size_t)N*64*4);
  unsigned* mb   = (unsigned*)alloc((size_t)N*64*4);
  unsigned* h_a  = (unsigned*)alloc((size_t)N*64*4);
  unsigned* h_b  = (unsigned*)alloc((size_t)N*64*4);
  unsigned* ylb  = (unsigned*)alloc((size_t)N*32*4);
  unsigned short* Bpk0 = (unsigned short*)alloc((size_t)256*dout[0]*2);
  unsigned short* Bpk1 = (unsigned short*)alloc((size_t)256*dout[1]*2);
  unsigned short* BpkL = (unsigned short*)alloc((size_t)128*dout[2]*2);
  unsigned short* BpkR = (unsigned short*)alloc((size_t)128*dout[2]*2);
  float* sc[3]; float* sh[3];
  for (int i=0;i<3;i++){
    sc[i] = (float*)alloc((size_t)dout[i]*4);
    sh[i] = (float*)alloc((size_t)dout[i]*4);
  }

  hipMemsetAsync(bz, 0, (size_t)2*nbuck*4, stream);

  WtpArgs wa[4];
  wa[0] = { Wl[0], Wr[0], bl[0], g[0], bb[0], rm[0], rv[0], Bpk0, sc[0], sh[0], 8, dout[0], 1, CDIV(256*dout[0]+dout[0],256) };
  wa[1] = { Wl[1], Wr[1], bl[1], g[1], bb[1], rm[1], rv[1], Bpk1, sc[1], sh[1], 8, dout[1], 1, CDIV(256*dout[1]+dout[1],256) };
  wa[2] = { Wl[2], nullptr, nullptr, nullptr, nullptr, nullptr, nullptr, BpkL, nullptr, nullptr, 4, dout[2], 0, CDIV(128*dout[2],256) };
  wa[3] = { Wr[2], nullptr, bl[2], g[2], bb[2], rm[2], rv[2], BpkR, sc[2], sh[2], 4, dout[2], 1, CDIV(128*dout[2]+dout[2],256) };

  int castBlocks = CDIV(N*64, 256);
  int histBlocks = CDIV(E, 256*16);
  int prepBlocks = castBlocks + histBlocks + wa[0].nblk + wa[1].nblk + wa[2].nblk + wa[3].nblk;
  k_prep   <<<prepBlocks,256,0,stream>>>(x, N*64, xb, edst, E, bcnt, nbuck, castBlocks, histBlocks,
                                         wa[0], wa[1], wa[2], wa[3]);
  k_bscan  <<<1,256,0,stream>>>(bcnt, nbuck, bbase);
  k_bucketA<<<CDIV(E,256*16),256,0,stream>>>(esrc, edst, E, bbase, bcur, ebuf, nbuck);
  k_bucketB<<<nbuck,256,0,stream>>>(ebuf, bbase, N, off, csr);

  int gemmGrid = CDIV(N, 64);
  // layer 0
  k_agg<<<CDIV(N*16,256),256,0,stream>>>((const uint4*)xb, off, csr, N, (uint4*)mb);
  k_gemm_hid<false><<<gemmGrid,256,0,stream>>>((const unsigned short*)mb, (const unsigned short*)xb,
                                               Bpk0, sc[0], sh[0], nullptr,
                                               (unsigned short*)h_a, nullptr, N);
  // layer 1 (+ fused yl = h_b @ Wl2^T)
  k_agg<<<CDIV(N*16,256),256,0,stream>>>((const uint4*)h_a, off, csr, N, (uint4*)mb);
  k_gemm_hid<true><<<gemmGrid,256,0,stream>>>((const unsigned short*)mb, (const unsigned short*)h_a,
                                              Bpk1, sc[1], sh[1], BpkL,
                                              (unsigned short*)h_b, (unsigned short*)ylb, N);
  // layer 2: fused mean-yl gather + final GEMM + BN + L2norm
  k_aggf<<<gemmGrid,256,0,stream>>>((const uint4*)ylb, off, csr,
                                    (const unsigned short*)h_b, BpkR, sc[2], sh[2],
                                    (float*)d_out, N);
}